// Round 7
// baseline (90.302 us; speedup 1.0000x reference)
//
#include <hip/hip_runtime.h>
#include <hip/hip_bf16.h>

#define D_IN 1386
#define EPS 1e-5f
#define CHUNKS 44            // ceil(1386/32)

typedef __attribute__((ext_vector_type(8))) short short8v;
typedef __attribute__((ext_vector_type(4))) float f32x4;
typedef unsigned short ushortt;

__device__ inline unsigned short bf16rne(float f) {
    unsigned int u = __float_as_uint(f);
    u += 0x7FFFu + ((u >> 16) & 1u);
    return (unsigned short)(u >> 16);
}
__device__ inline float bfbits_to_f(unsigned short b) {
    return __uint_as_float(((unsigned int)b) << 16);
}

union S8U { short8v s; unsigned int u[4]; };

// packed pair f32->bf16 (RNE, v_cvt_pk_bf16_f32) + residuals
__device__ inline unsigned int cvt2(float v0, float v1, float& r0, float& r1) {
    union { __hip_bfloat162 b2; unsigned int u; } cv;
    cv.b2 = __float22bfloat162_rn(make_float2(v0, v1));
    r0 = v0 - __uint_as_float((cv.u & 0xFFFFu) << 16);
    r1 = v1 - __uint_as_float(cv.u & 0xFFFF0000u);
    return cv.u;
}
__device__ inline unsigned int cvt2n(float v0, float v1) {
    union { __hip_bfloat162 b2; unsigned int u; } cv;
    cv.b2 = __float22bfloat162_rn(make_float2(v0, v1));
    return cv.u;
}

// ---------------- Kernel 0: precompute triple-split W1 in frag-image order --
// short index: c*6144 + (3T+s)*512 + l*8 + j -> split_s( w[16T+(l&15)][32c+8*(l>>4)+j] )
__global__ __launch_bounds__(256) void prep_w3(const float* __restrict__ w,
                                               ushortt* __restrict__ w3) {
    int idx = blockIdx.x * 256 + threadIdx.x;
    if (idx >= CHUNKS * 6144) return;
    int c   = idx / 6144;
    int rem = idx - c * 6144;
    int g   = rem >> 9;
    int l   = (rem >> 3) & 63;
    int j   = rem & 7;
    int T   = g / 3, s = g - 3 * T;
    int h   = 16 * T + (l & 15);
    int k   = 32 * c + 8 * (l >> 4) + j;
    float v = (k < D_IN) ? w[h * D_IN + k] : 0.f;
    unsigned short hh = bf16rne(v);
    float r1 = v - bfbits_to_f(hh);
    unsigned short mm = bf16rne(r1);
    float r2 = r1 - bfbits_to_f(mm);
    unsigned short ll = bf16rne(r2);
    w3[idx] = (s == 0) ? hh : (s == 1) ? mm : ll;
}

// ---------------- Kernel 1: y = x @ fc1_w.T --------------------------------
// Wave = 16 samples x 16 h x FULL K (44 chunks). Block = 8 waves = 2 sample-
// tiles (mt) x 4 h-tiles (T); the 4 T-waves of one mt read identical x
// addresses -> L1 broadcast (x traffic stays 91 MB). Grid 512x512thr ->
// 4096 waves = 4/SIMD. No LDS, no barriers, no reduction. Even/odd static
// register pipeline (load->use distance = 1 full body).
__global__ __launch_bounds__(512, 4) void fc1_mfma(const float* __restrict__ x,
                                                   const ushortt* __restrict__ w3,
                                                   float* __restrict__ y) {
    const int lane = threadIdx.x & 63;
    const int wid  = threadIdx.x >> 6;
    const int T    = wid & 3;            // h-tile
    const int mt   = wid >> 2;           // sample-tile within block
    const int n0   = blockIdx.x * 32 + mt * 16;
    const int r    = lane & 15;
    const int g4   = lane >> 4;
    const float* xrow = x + (size_t)(n0 + r) * D_IN + 8 * g4;
    const ushortt* wT = w3 + 3 * T * 512;   // this wave's 3 frag-groups

    f32x4 acc = (f32x4){0.f, 0.f, 0.f, 0.f};

    float aE[8], aO[8];
    short8v BE[3], BO[3];

    auto loadAx = [&](int c, float (&a)[8]) {
        if (c < CHUNKS - 1) {
            const float2* p = (const float2*)(xrow + 32 * c);
#pragma unroll
            for (int i = 0; i < 4; ++i) {
                float2 v = p[i]; a[2 * i] = v.x; a[2 * i + 1] = v.y;
            }
        } else {
#pragma unroll
            for (int j = 0; j < 8; ++j) {
                int kk = 8 * g4 + j;                       // +1376 = global k
                a[j] = (kk < D_IN - 32 * (CHUNKS - 1)) ? xrow[32 * (CHUNKS - 1) + j] : 0.f;
            }
        }
    };
    auto loadBx = [&](int c, short8v (&B)[3]) {
        const short8v* bp = (const short8v*)(wT + (size_t)c * 6144) + lane;
#pragma unroll
        for (int s = 0; s < 3; ++s) B[s] = bp[s * 64];
    };
    auto body = [&](float (&a)[8], short8v (&B)[3]) {
        S8U Ah, Am, Al;
#pragma unroll
        for (int d = 0; d < 4; ++d) {
            float m0, m1, l0, l1;
            Ah.u[d] = cvt2(a[2 * d], a[2 * d + 1], m0, m1);
            Am.u[d] = cvt2(m0, m1, l0, l1);
            Al.u[d] = cvt2n(l0, l1);
        }
        const short8v XH = Ah.s, XM = Am.s, XL = Al.s;
        const short8v Bh = B[0], Bm = B[1], Bl = B[2];
        acc = __builtin_amdgcn_mfma_f32_16x16x32_bf16(XL, Bh, acc, 0, 0, 0);
        acc = __builtin_amdgcn_mfma_f32_16x16x32_bf16(XM, Bm, acc, 0, 0, 0);
        acc = __builtin_amdgcn_mfma_f32_16x16x32_bf16(XH, Bl, acc, 0, 0, 0);
        acc = __builtin_amdgcn_mfma_f32_16x16x32_bf16(XM, Bh, acc, 0, 0, 0);
        acc = __builtin_amdgcn_mfma_f32_16x16x32_bf16(XH, Bm, acc, 0, 0, 0);
        acc = __builtin_amdgcn_mfma_f32_16x16x32_bf16(XH, Bh, acc, 0, 0, 0);
    };

    loadAx(0, aE); loadBx(0, BE);
    loadAx(1, aO); loadBx(1, BO);

    for (int j = 0; j < CHUNKS / 2; ++j) {
        body(aE, BE);
        if (2 * j + 2 < CHUNKS) { loadAx(2 * j + 2, aE); loadBx(2 * j + 2, BE); }
        body(aO, BO);
        if (2 * j + 3 < CHUNKS) { loadAx(2 * j + 3, aO); loadBx(2 * j + 3, BO); }
    }

    // D layout: row (sample) = 4*g4+q, col (h) = 16T + r
#pragma unroll
    for (int q = 0; q < 4; ++q)
        y[(size_t)(n0 + 4 * g4 + q) * 64 + 16 * T + r] = acc[q];
}

// ---------------- Kernel 2: 64-step LIF recurrence, h'-split 4 ways ---------
// Block = 4 waves x 16 samples; wave T owns h' in [16T,16T+16). All LIF state
// lane-local in D layout (sample = lane&15, h' = 16T+4*grp+q). Spikes
// exchanged per step via double-buffered LDS (1 barrier/step).
// Grid 1024 -> 4096 waves = 4/SIMD.
__global__ __launch_bounds__(256, 4) void snn_kernel(
    const float* __restrict__ y,
    const float* __restrict__ fc1_b,
    const float* __restrict__ bn1_g, const float* __restrict__ bn1_b,
    const float* __restrict__ bn1_m, const float* __restrict__ bn1_v,
    const float* __restrict__ fc2_w, const float* __restrict__ fc2_b,
    const float* __restrict__ bn2_g, const float* __restrict__ bn2_b,
    const float* __restrict__ bn2_m, const float* __restrict__ bn2_v,
    const float* __restrict__ cls_w, const float* __restrict__ cls_b,
    float* __restrict__ out)
{
    __shared__ unsigned int spk[2][16][36];   // [buf][sample][h/2], pad 36
    __shared__ float redc[4][16][4];
    const int lane = threadIdx.x & 63;
    const int T    = threadIdx.x >> 6;       // h'-tile of this wave
    const int n0   = blockIdx.x * 16;
    const int r    = lane & 15;              // sample
    const int grp  = lane >> 4;

    // A fragments: W2'[h'][k] rows [16T,16T+16), bn2 folded, hi/lo split
    short8v Whi[2], Wlo[2];
    {
        const int hp = 16 * T + r;
        const float scale = bn2_g[hp] / sqrtf(bn2_v[hp] + EPS);
#pragma unroll
        for (int Hh = 0; Hh < 2; ++Hh) {
            S8U hi, lo;
#pragma unroll
            for (int d = 0; d < 4; ++d) {
                const int kk = 32 * Hh + 8 * grp + 2 * d;
                float w0 = fc2_w[hp * 64 + kk]     * scale;
                float w1 = fc2_w[hp * 64 + kk + 1] * scale;
                unsigned short h0 = bf16rne(w0), h1 = bf16rne(w1);
                unsigned short l0 = bf16rne(w0 - bfbits_to_f(h0));
                unsigned short l1 = bf16rne(w1 - bfbits_to_f(h1));
                hi.u[d] = (unsigned int)h0 | ((unsigned int)h1 << 16);
                lo.u[d] = (unsigned int)l0 | ((unsigned int)l1 << 16);
            }
            Whi[Hh] = hi.s;
            Wlo[Hh] = lo.s;
        }
    }

    // a1 + bias2' at h' = 16T + 4*grp + q (D layout, lane-local)
    const int h0 = 16 * T + 4 * grp;
    float a1[4], biasD[4];
    {
        float4 yv = *(const float4*)&y[(size_t)(n0 + r) * 64 + h0];
#pragma unroll
        for (int q = 0; q < 4; ++q) {
            const int h = h0 + q;
            float s1v = bn1_g[h] / sqrtf(bn1_v[h] + EPS);
            float yq  = (q == 0) ? yv.x : (q == 1) ? yv.y : (q == 2) ? yv.z : yv.w;
            a1[q] = (yq + fc1_b[h] - bn1_m[h]) * s1v + bn1_b[h];
            const float s2v = bn2_g[h] / sqrtf(bn2_v[h] + EPS);
            biasD[q] = (fc2_b[h] - bn2_m[h]) * s2v + bn2_b[h];
        }
    }

    float v1[4], v2[4], cnt[4];
#pragma unroll
    for (int q = 0; q < 4; ++q) { v1[q] = 0.f; v2[q] = 0.f; cnt[q] = 0.f; }

    for (int t = 0; t < 64; ++t) {
        const int b = t & 1;
        // LIF1 on own h'-slice + pack spikes as bf16 {0,1} pairs
        unsigned int dw0, dw1;
        {
            float h1a = v1[0] + (a1[0] - v1[0]) * 0.5f;
            float h1b = v1[1] + (a1[1] - v1[1]) * 0.5f;
            float h1c = v1[2] + (a1[2] - v1[2]) * 0.5f;
            float h1d = v1[3] + (a1[3] - v1[3]) * 0.5f;
            bool sa = h1a >= 1.f, sb = h1b >= 1.f, sc = h1c >= 1.f, sd = h1d >= 1.f;
            v1[0] = sa ? 0.f : h1a; v1[1] = sb ? 0.f : h1b;
            v1[2] = sc ? 0.f : h1c; v1[3] = sd ? 0.f : h1d;
            dw0 = (sa ? 0x3F80u : 0u) | (sb ? 0x3F800000u : 0u);
            dw1 = (sc ? 0x3F80u : 0u) | (sd ? 0x3F800000u : 0u);
        }
        *(uint2*)&spk[b][r][8 * T + 2 * grp] = make_uint2(dw0, dw1);
        __syncthreads();
        // B fragments: lane needs s[sample=r][k=8*grp+j] (S0), +32 (S1)
        uint4 wv0 = *(const uint4*)&spk[b][r][4 * grp];
        uint4 wv1 = *(const uint4*)&spk[b][r][16 + 4 * grp];
        S8U s0u, s1u;
        s0u.u[0] = wv0.x; s0u.u[1] = wv0.y; s0u.u[2] = wv0.z; s0u.u[3] = wv0.w;
        s1u.u[0] = wv1.x; s1u.u[1] = wv1.y; s1u.u[2] = wv1.z; s1u.u[3] = wv1.w;
        const short8v S0 = s0u.s, S1 = s1u.s;

        f32x4 c1;
        c1[0] = biasD[0]; c1[1] = biasD[1]; c1[2] = biasD[2]; c1[3] = biasD[3];
        f32x4 c2 = (f32x4){0.f, 0.f, 0.f, 0.f};
        c1 = __builtin_amdgcn_mfma_f32_16x16x32_bf16(Whi[0], S0, c1, 0, 0, 0);
        c2 = __builtin_amdgcn_mfma_f32_16x16x32_bf16(Wlo[0], S0, c2, 0, 0, 0);
        c1 = __builtin_amdgcn_mfma_f32_16x16x32_bf16(Whi[1], S1, c1, 0, 0, 0);
        c2 = __builtin_amdgcn_mfma_f32_16x16x32_bf16(Wlo[1], S1, c2, 0, 0, 0);

        // LIF2 + spike count (lane-local)
#pragma unroll
        for (int q = 0; q < 4; ++q) {
            float z  = c1[q] + c2[q];
            float h2 = v2[q] + (z - v2[q]) * 0.5f;
            bool s = h2 >= 1.f;
            v2[q] = s ? 0.f : h2;
            cnt[q] += s ? 1.f : 0.f;
        }
    }

    // classifier: partial over this wave's 16 h', reduce grp via shfl, T via LDS
    float p[4];
#pragma unroll
    for (int c = 0; c < 4; ++c) {
        p[c] = cnt[0] * cls_w[c * 64 + h0]     + cnt[1] * cls_w[c * 64 + h0 + 1]
             + cnt[2] * cls_w[c * 64 + h0 + 2] + cnt[3] * cls_w[c * 64 + h0 + 3];
        p[c] += __shfl_xor(p[c], 16);
        p[c] += __shfl_xor(p[c], 32);
    }
    if (lane < 16) {
        float4 v; v.x = p[0]; v.y = p[1]; v.z = p[2]; v.w = p[3];
        *(float4*)&redc[T][lane][0] = v;
    }
    __syncthreads();
    if (threadIdx.x < 16) {
        const int s = threadIdx.x;
        float4 o;
        o.x = (redc[0][s][0] + redc[1][s][0] + redc[2][s][0] + redc[3][s][0]) * (1.f / 64.f) + cls_b[0];
        o.y = (redc[0][s][1] + redc[1][s][1] + redc[2][s][1] + redc[3][s][1]) * (1.f / 64.f) + cls_b[1];
        o.z = (redc[0][s][2] + redc[1][s][2] + redc[2][s][2] + redc[3][s][2]) * (1.f / 64.f) + cls_b[2];
        o.w = (redc[0][s][3] + redc[1][s][3] + redc[2][s][3] + redc[3][s][3]) * (1.f / 64.f) + cls_b[3];
        *(float4*)&out[(size_t)(n0 + s) * 4] = o;
    }
}

extern "C" void kernel_launch(void* const* d_in, const int* in_sizes, int n_in,
                              void* d_out, int out_size, void* d_ws, size_t ws_size,
                              hipStream_t stream) {
    const float* x     = (const float*)d_in[0];
    const float* fc1_w = (const float*)d_in[1];
    const float* fc1_b = (const float*)d_in[2];
    const float* bn1_g = (const float*)d_in[3];
    const float* bn1_b = (const float*)d_in[4];
    const float* bn1_m = (const float*)d_in[5];
    const float* bn1_v = (const float*)d_in[6];
    const float* fc2_w = (const float*)d_in[7];
    const float* fc2_b = (const float*)d_in[8];
    const float* bn2_g = (const float*)d_in[9];
    const float* bn2_b = (const float*)d_in[10];
    const float* bn2_m = (const float*)d_in[11];
    const float* bn2_v = (const float*)d_in[12];
    const float* cls_w = (const float*)d_in[13];
    const float* cls_b = (const float*)d_in[14];

    float*   y  = (float*)d_ws;                            // 4 MB
    ushortt* w3 = (ushortt*)((char*)d_ws + (4 << 20));     // 528 KB

    prep_w3 <<<1056, 256, 0, stream>>>(fc1_w, w3);
    fc1_mfma<<<512,  512, 0, stream>>>(x, w3, y);
    snn_kernel<<<1024, 256, 0, stream>>>(y, fc1_b, bn1_g, bn1_b, bn1_m, bn1_v,
                                         fc2_w, fc2_b, bn2_g, bn2_b, bn2_m, bn2_v,
                                         cls_w, cls_b, (float*)d_out);
}